// Round 19
// baseline (316.414 us; speedup 1.0000x reference)
//
#include <hip/hip_runtime.h>
#include <math.h>

#define NPTS 8192
#define NB 2
#define DF 64
#define HID 128
#define OUTC 64
#define KNN 16

typedef __attribute__((ext_vector_type(8))) short short8v;   // 8 bf16 (4 VGPRs)
typedef __attribute__((ext_vector_type(4))) float f32x4;

__device__ __forceinline__ unsigned short f2bf(float f) {    // f32 -> bf16 RNE
  unsigned int u = __float_as_uint(f);
  u += 0x7fffu + ((u >> 16) & 1u);
  return (unsigned short)(u >> 16);
}

__device__ __forceinline__ float readlane_f(float v, int l) {
  return __uint_as_float(__builtin_amdgcn_readlane(__float_as_uint(v), l));
}

// ---------------- prep: pack points as float4(x,y,z,0)
__global__ void k_prep(const float* __restrict__ xyz1, const float* __restrict__ xyz2,
                       const float* __restrict__ flow1,
                       float4* __restrict__ A, float4* __restrict__ Bq, float4* __restrict__ Qx) {
  int t = blockIdx.x * 256 + threadIdx.x;      // 0..16383
  int b = t >> 13, n = t & (NPTS - 1);
  size_t base = (size_t)b * 3 * NPTS + n;
  float x1 = xyz1[base], y1 = xyz1[base + NPTS], z1 = xyz1[base + 2 * NPTS];
  float fx = flow1[base], fy = flow1[base + NPTS], fz = flow1[base + 2 * NPTS];
  float sx = x1 + fx, sy = y1 + fy, sz = z1 + fz;
  A[t]  = make_float4(sx, sy, sz, 0.f);
  Bq[t] = make_float4(x1, y1, z1, 0.f);
  float x2 = xyz2[base], y2 = xyz2[base + NPTS], z2 = xyz2[base + 2 * NPTS];
  Qx[t] = make_float4(x2, y2, z2, 0.f);
}

// ---------------- feat2 [B,D,N] -> F [B,N,D]
__global__ void k_feat_T(const float* __restrict__ feat2, float* __restrict__ F) {
  __shared__ float t[64][65];
  int b = blockIdx.y;
  int n0 = blockIdx.x * 64;
  int l = threadIdx.x & 63, w = threadIdx.x >> 6;
#pragma unroll
  for (int it = 0; it < 16; ++it) {
    int dd = w + it * 4;
    t[dd][l] = feat2[((size_t)b * DF + dd) * NPTS + n0 + l];
  }
  __syncthreads();
#pragma unroll
  for (int it = 0; it < 16; ++it) {
    int nn = w + it * 4;
    F[((size_t)b * NPTS + n0 + nn) * DF + l] = t[l][nn];
  }
}

// ---------------- W1 [128][67] -> W1T [67][128]
__global__ void k_w1t(const float* __restrict__ W1, float* __restrict__ W1T) {
  int t = blockIdx.x * 256 + threadIdx.x;
  if (t >= 67 * 128) return;
  int c = t >> 7, h = t & 127;
  W1T[t] = W1[h * 67 + c];
}

// ---------------- W2 [64][128] -> bf16 fragment order: frag=(step*4+ot), lane, j
__global__ void k_w2frag(const float* __restrict__ W2, unsigned short* __restrict__ W2f) {
  int t = blockIdx.x * 256 + threadIdx.x;   // 0..1023
  if (t >= 1024) return;
  int frag = t >> 6, lane = t & 63;
  int step = frag >> 2, ot = frag & 3;
  int col = ot * 16 + (lane & 15);
  int k0 = step * 32 + (lane >> 4) * 8;
#pragma unroll
  for (int j = 0; j < 8; ++j)
    W2f[t * 8 + j] = f2bf(W2[col * HID + k0 + j]);
}

// ---------------- Hfeat[pt][h] = b1[h] + sum_c F[pt][c] * W1T[3+c][h]
__global__ void k_hfeat(const float* __restrict__ F, const float* __restrict__ W1T,
                        const float* __restrict__ b1, float* __restrict__ Hfeat) {
  int tid = threadIdx.x;
  int pt = blockIdx.x * 2 + (tid >> 7);     // 2 points per 256-thread block
  int h = tid & 127;
  const float* fr = F + (size_t)pt * DF;
  float a = b1[h];
#pragma unroll
  for (int c = 0; c < DF; ++c) a = fmaf(fr[c], W1T[(3 + c) * HID + h], a);
  Hfeat[(size_t)pt * HID + h] = a;          // NO leaky (xyz part added later)
}

// ---------------- bitonic full-sort of 64 (d,idx) pairs across lanes, lex ascending
__device__ __forceinline__ void bitonic64(float& d, int& i, int lane) {
#pragma unroll
  for (int k2 = 2; k2 <= 64; k2 <<= 1) {
#pragma unroll
    for (int j2 = k2 >> 1; j2 > 0; j2 >>= 1) {
      float pd = __shfl_xor(d, j2);
      int   pi = __shfl_xor(i, j2);
      bool swp = (pd < d) || (pd == d && pi < i);           // partner strictly smaller
      bool take = (((lane & k2) == 0) == ((lane & j2) == 0)) ? swp : !swp;
      d = take ? pd : d;
      i = take ? pi : i;
    }
  }
}

// ---------------- flush buffer (cnt entries) into the sorted 64-list, tighten cap
// list asc + sorted buffer asc: reversed-buffer elementwise lex-min keeps the
// exact lowest 64 of the 128 union (bitonic half-cleaner), then 6-stage merge.
template<int K>
__device__ __forceinline__ void flush_merge(const float* bufD, const int* bufJ, int base,
                                            int cnt, int lane,
                                            float& ld, int& li, float& cap) {
  float bd = (lane < cnt) ? bufD[base + lane] : __builtin_inff();
  int   bj = (lane < cnt) ? bufJ[base + lane] : 0x7fffffff;
  bitonic64(bd, bj, lane);
  float rd = __shfl_xor(bd, 63);            // reverse -> descending
  int   rj = __shfl_xor(bj, 63);
  bool tk = (rd < ld) || (rd == ld && rj < li);
  float nd = tk ? rd : ld;
  int   nj = tk ? rj : li;
#pragma unroll
  for (int j2 = 32; j2 >= 1; j2 >>= 1) {    // bitonic merge, ascending
    float pd = __shfl_xor(nd, j2);
    int   pi = __shfl_xor(nj, j2);
    bool sm = (pd < nd) || (pd == nd && pi < nj);
    bool take = ((lane & j2) == 0) ? sm : !sm;
    nd = take ? pd : nd;
    nj = take ? pi : nj;
  }
  ld = nd; li = nj;
  cap = readlane_f(ld, K - 1);
}

// ================ LDS-staged exact KNN with batched candidate buffering ========
// Block = 4 waves = 8 queries; 2048 blocks -> 8 blocks/CU. LDS = 8KB tile +
// 4KB buffers = 12.25KB -> 13 blocks/CU capacity, so all 8 resident (r18's
// 20.5KB allocation fit only 7 -> straggler phase, Occ 49%). 16 chunks of 512.
// adm frozen before flush: ballot/rank/write consistent; superset admission,
// exactness from lex-sorted merges (ties -> lowest index, jax semantics).
template<int K>
__global__ void __launch_bounds__(256) k_knn_buf(const float4* __restrict__ db,
                                                 const float4* __restrict__ qry,
                                                 int* __restrict__ outIdx) {
  __shared__ float4 tile[512];
  __shared__ float bufD[512];
  __shared__ int   bufJ[512];
  int bk = blockIdx.x;                       // 0..2047
  int b = bk >> 10;                          // batch (1024 blocks each)
  int wave = threadIdx.x >> 6, lane = threadIdx.x & 63;
  int qb = bk * 8 + wave * 2;
  float4 Q0 = qry[qb], Q1 = qry[qb + 1];
  const float4* dbase = db + (size_t)b * NPTS;
  int base0 = (wave * 2 + 0) * 64, base1 = (wave * 2 + 1) * 64;

#pragma unroll
  for (int i = 0; i < 2; ++i) tile[threadIdx.x + i * 256] = dbase[threadIdx.x + i * 256];
  __syncthreads();

  // bootstrap: bitonic-sort distances to points 0..63
  float ld0, ld1; int li0 = lane, li1 = lane;
  {
    float4 p = tile[lane];
    float dx = Q0.x - p.x, dy = Q0.y - p.y, dz = Q0.z - p.z;
    ld0 = fmaf(dx, dx, fmaf(dy, dy, dz * dz));
    dx = Q1.x - p.x; dy = Q1.y - p.y; dz = Q1.z - p.z;
    ld1 = fmaf(dx, dx, fmaf(dy, dy, dz * dz));
  }
  bitonic64(ld0, li0, lane);
  bitonic64(ld1, li1, lane);
  float cap0 = readlane_f(ld0, K - 1), cap1 = readlane_f(ld1, K - 1);
  int cnt0 = 0, cnt1 = 0;

  for (int chunk = 0; chunk < 16; ++chunk) {
    if (chunk) {
      __syncthreads();
#pragma unroll
      for (int i = 0; i < 2; ++i)
        tile[threadIdx.x + i * 256] = dbase[chunk * 512 + threadIdx.x + i * 256];
      __syncthreads();
    }
    for (int it = (chunk == 0) ? 1 : 0; it < 8; ++it) {
      int j = chunk * 512 + it * 64 + lane;
      float4 p = tile[it * 64 + lane];
      float ax = Q0.x - p.x, ay = Q0.y - p.y, az = Q0.z - p.z;
      float d0 = fmaf(ax, ax, fmaf(ay, ay, az * az));
      float bx = Q1.x - p.x, by = Q1.y - p.y, bz = Q1.z - p.z;
      float d1 = fmaf(bx, bx, fmaf(by, by, bz * bz));

      bool adm0 = d0 <= cap0;                      // frozen BEFORE any flush
      unsigned long long m0 = __ballot(adm0);
      if (m0) {
        int pc = __popcll(m0);
        if (cnt0 + pc > 64) {
          flush_merge<K>(bufD, bufJ, base0, cnt0, lane, ld0, li0, cap0);
          cnt0 = 0;
        }
        int rank = __popcll(m0 & ((1ull << lane) - 1ull));
        if (adm0) { bufD[base0 + cnt0 + rank] = d0; bufJ[base0 + cnt0 + rank] = j; }
        cnt0 += pc;
      }
      bool adm1 = d1 <= cap1;                      // frozen BEFORE any flush
      unsigned long long m1 = __ballot(adm1);
      if (m1) {
        int pc = __popcll(m1);
        if (cnt1 + pc > 64) {
          flush_merge<K>(bufD, bufJ, base1, cnt1, lane, ld1, li1, cap1);
          cnt1 = 0;
        }
        int rank = __popcll(m1 & ((1ull << lane) - 1ull));
        if (adm1) { bufD[base1 + cnt1 + rank] = d1; bufJ[base1 + cnt1 + rank] = j; }
        cnt1 += pc;
      }
    }
  }
  if (cnt0) flush_merge<K>(bufD, bufJ, base0, cnt0, lane, ld0, li0, cap0);
  if (cnt1) flush_merge<K>(bufD, bufJ, base1, cnt1, lane, ld1, li1, cap1);

  if (lane < K) {
    outIdx[(qb + 0) * K + lane] = li0;
    outIdx[(qb + 1) * K + lane] = li1;
  }
}

// ---------------- 3-NN inverse-distance warp interpolation
__global__ void k_warp_finish(const int* __restrict__ idx3,
                              const float4* __restrict__ A, const float4* __restrict__ Qx,
                              const float* __restrict__ flow1, float* __restrict__ out1,
                              float4* __restrict__ C) {
  int qg = blockIdx.x * 256 + threadIdx.x;
  int b = qg >> 13, n = qg & (NPTS - 1);
  int idx[3];
#pragma unroll
  for (int r = 0; r < 3; ++r) idx[r] = idx3[qg * 3 + r];
  float4 q = Qx[qg];
  float ivd[3];
  float s = 0.f;
#pragma unroll
  for (int r = 0; r < 3; ++r) {
    float4 p = A[b * NPTS + idx[r]];
    float gx = p.x - q.x, gy = p.y - q.y, gz = p.z - q.z;
    float dist = sqrtf(gx * gx + gy * gy + gz * gz);
    dist = fmaxf(dist, 1e-10f);
    ivd[r] = 1.0f / dist;
    s += ivd[r];
  }
  float w0 = ivd[0] / s, w1 = ivd[1] / s, w2 = ivd[2] / s;
  size_t fb = (size_t)b * 3 * NPTS;
  float f2x = w0 * flow1[fb + idx[0]]            + w1 * flow1[fb + idx[1]]            + w2 * flow1[fb + idx[2]];
  float f2y = w0 * flow1[fb + NPTS + idx[0]]     + w1 * flow1[fb + NPTS + idx[1]]     + w2 * flow1[fb + NPTS + idx[2]];
  float f2z = w0 * flow1[fb + 2 * NPTS + idx[0]] + w1 * flow1[fb + 2 * NPTS + idx[1]] + w2 * flow1[fb + 2 * NPTS + idx[2]];
  float wx = q.x - f2x, wy = q.y - f2y, wz = q.z - f2z;
  out1[fb + n] = wx;
  out1[fb + NPTS + n] = wy;
  out1[fb + 2 * NPTS + n] = wz;
  C[qg] = make_float4(wx, wy, wz, 0.f);
}

// ---------------- MFMA MLP (unchanged)
__global__ void __launch_bounds__(256) k_mlp3(const int* __restrict__ Didx, const float4* __restrict__ C,
                                              const float4* __restrict__ Bq, const float* __restrict__ Hfeat,
                                              const float* __restrict__ W1T, const unsigned short* __restrict__ W2f,
                                              const float* __restrict__ b2, float* __restrict__ out0) {
  int lane = threadIdx.x & 63;
  int wg = blockIdx.x * 4 + (threadIdx.x >> 6);    // 0..4095, 4 q per wave
  int fr = lane & 15, fq = lane >> 4;

  short8v Bfr[16];
  const short8v* wf = (const short8v*)W2f;
#pragma unroll
  for (int i = 0; i < 16; ++i) Bfr[i] = wf[i * 64 + lane];
  float b2v0 = b2[fr], b2v1 = b2[16 + fr], b2v2 = b2[32 + fr], b2v3 = b2[48 + fr];

  for (int iq = 0; iq < 4; ++iq) {
    int q = wg * 4 + iq;
    int b = q >> 13, n = q & (NPTS - 1);
    int idx = Didx[q * KNN + fr];
    float4 wp = C[b * NPTS + idx];
    float4 qp = Bq[q];
    float dx = wp.x - qp.x, dy = wp.y - qp.y, dz = wp.z - qp.z;
    const float* hf = Hfeat + ((size_t)(b * NPTS + idx)) * HID;

    f32x4 acc0 = {b2v0, b2v0, b2v0, b2v0};
    f32x4 acc1 = {b2v1, b2v1, b2v1, b2v1};
    f32x4 acc2 = {b2v2, b2v2, b2v2, b2v2};
    f32x4 acc3 = {b2v3, b2v3, b2v3, b2v3};

#pragma unroll
    for (int step = 0; step < 4; ++step) {
      int k0 = step * 32 + fq * 8;
      float4 ha = *(const float4*)(hf + k0);
      float4 hb = *(const float4*)(hf + k0 + 4);
      float4 wx0 = *(const float4*)(W1T + k0);
      float4 wx1 = *(const float4*)(W1T + k0 + 4);
      float4 wy0 = *(const float4*)(W1T + HID + k0);
      float4 wy1 = *(const float4*)(W1T + HID + k0 + 4);
      float4 wz0 = *(const float4*)(W1T + 2 * HID + k0);
      float4 wz1 = *(const float4*)(W1T + 2 * HID + k0 + 4);
      float h[8];
      h[0] = fmaf(dx, wx0.x, fmaf(dy, wy0.x, fmaf(dz, wz0.x, ha.x)));
      h[1] = fmaf(dx, wx0.y, fmaf(dy, wy0.y, fmaf(dz, wz0.y, ha.y)));
      h[2] = fmaf(dx, wx0.z, fmaf(dy, wy0.z, fmaf(dz, wz0.z, ha.z)));
      h[3] = fmaf(dx, wx0.w, fmaf(dy, wy0.w, fmaf(dz, wz0.w, ha.w)));
      h[4] = fmaf(dx, wx1.x, fmaf(dy, wy1.x, fmaf(dz, wz1.x, hb.x)));
      h[5] = fmaf(dx, wx1.y, fmaf(dy, wy1.y, fmaf(dz, wz1.y, hb.y)));
      h[6] = fmaf(dx, wx1.z, fmaf(dy, wy1.z, fmaf(dz, wz1.z, hb.z)));
      h[7] = fmaf(dx, wx1.w, fmaf(dy, wy1.w, fmaf(dz, wz1.w, hb.w)));
      short8v a;
#pragma unroll
      for (int j = 0; j < 8; ++j) {
        float v = h[j];
        v = v >= 0.f ? v : 0.1f * v;
        a[j] = (short)f2bf(v);
      }
      acc0 = __builtin_amdgcn_mfma_f32_16x16x32_bf16(a, Bfr[step * 4 + 0], acc0, 0, 0, 0);
      acc1 = __builtin_amdgcn_mfma_f32_16x16x32_bf16(a, Bfr[step * 4 + 1], acc1, 0, 0, 0);
      acc2 = __builtin_amdgcn_mfma_f32_16x16x32_bf16(a, Bfr[step * 4 + 2], acc2, 0, 0, 0);
      acc3 = __builtin_amdgcn_mfma_f32_16x16x32_bf16(a, Bfr[step * 4 + 3], acc3, 0, 0, 0);
    }

    int ob = (b * OUTC) * NPTS + n;
#pragma unroll
    for (int ot = 0; ot < 4; ++ot) {
      f32x4 ac = ot == 0 ? acc0 : (ot == 1 ? acc1 : (ot == 2 ? acc2 : acc3));
      float m = fmaxf(fmaxf(ac[0], ac[1]), fmaxf(ac[2], ac[3]));
      m = fmaxf(m, __shfl_xor(m, 16));
      m = fmaxf(m, __shfl_xor(m, 32));
      m = m >= 0.f ? m : 0.1f * m;
      if (lane < 16) out0[ob + (ot * 16 + lane) * NPTS] = m;
    }
  }
}

extern "C" void kernel_launch(void* const* d_in, const int* in_sizes, int n_in,
                              void* d_out, int out_size, void* d_ws, size_t ws_size,
                              hipStream_t stream) {
  const float* xyz1  = (const float*)d_in[0];
  const float* xyz2  = (const float*)d_in[1];
  const float* flow1 = (const float*)d_in[2];
  const float* feat2 = (const float*)d_in[3];
  const float* W1    = (const float*)d_in[4];
  const float* b1    = (const float*)d_in[5];
  const float* W2    = (const float*)d_in[6];
  const float* b2    = (const float*)d_in[7];
  float* out0 = (float*)d_out;
  float* out1 = out0 + (size_t)NB * OUTC * NPTS;

  float* w = (float*)d_ws;
  float4* A     = (float4*)(w);             // 65536 floats
  float4* Bq    = (float4*)(w + 65536);
  float4* Qx    = (float4*)(w + 131072);
  float4* Cw    = (float4*)(w + 196608);
  float*  F     = w + 262144;               // 1048576
  float*  Hfeat = w + 1310720;              // 2097152
  float*  W1T   = w + 3407872;              // 16384 (8576 used)
  int*    idx3  = (int*)(w + 3424256);      // 49152
  int*    Didx  = (int*)(w + 3473408);      // 262144
  unsigned short* W2f = (unsigned short*)(w + 3735552);  // 8192 bf16

  k_prep<<<64, 256, 0, stream>>>(xyz1, xyz2, flow1, A, Bq, Qx);
  k_feat_T<<<dim3(128, 2), 256, 0, stream>>>(feat2, F);
  k_w1t<<<34, 256, 0, stream>>>(W1, W1T);
  k_w2frag<<<4, 256, 0, stream>>>(W2, W2f);
  k_hfeat<<<NB * NPTS / 2, 256, 0, stream>>>(F, W1T, b1, Hfeat);

  k_knn_buf<3><<<2048, 256, 0, stream>>>(A, Qx, idx3);
  k_warp_finish<<<64, 256, 0, stream>>>(idx3, A, Qx, flow1, out1, Cw);
  k_knn_buf<16><<<2048, 256, 0, stream>>>(Cw, Bq, Didx);
  k_mlp3<<<1024, 256, 0, stream>>>(Didx, Cw, Bq, Hfeat, W1T, W2f, b2, out0);
}

// Round 20
// 261.615 us; speedup vs baseline: 1.2095x; 1.2095x over previous
//
#include <hip/hip_runtime.h>
#include <math.h>

#define NPTS 8192
#define NB 2
#define DF 64
#define HID 128
#define OUTC 64
#define KNN 16

typedef __attribute__((ext_vector_type(8))) short short8v;   // 8 bf16 (4 VGPRs)
typedef __attribute__((ext_vector_type(4))) float f32x4;

__device__ __forceinline__ unsigned short f2bf(float f) {    // f32 -> bf16 RNE
  unsigned int u = __float_as_uint(f);
  u += 0x7fffu + ((u >> 16) & 1u);
  return (unsigned short)(u >> 16);
}

__device__ __forceinline__ float readlane_f(float v, int l) {
  return __uint_as_float(__builtin_amdgcn_readlane(__float_as_uint(v), l));
}
__device__ __forceinline__ int readlane_i(int v, int l) {
  return (int)__builtin_amdgcn_readlane((unsigned)v, l);
}

// ---------------- prep: pack points as float4(x,y,z,0)
__global__ void k_prep(const float* __restrict__ xyz1, const float* __restrict__ xyz2,
                       const float* __restrict__ flow1,
                       float4* __restrict__ A, float4* __restrict__ Bq, float4* __restrict__ Qx) {
  int t = blockIdx.x * 256 + threadIdx.x;      // 0..16383
  int b = t >> 13, n = t & (NPTS - 1);
  size_t base = (size_t)b * 3 * NPTS + n;
  float x1 = xyz1[base], y1 = xyz1[base + NPTS], z1 = xyz1[base + 2 * NPTS];
  float fx = flow1[base], fy = flow1[base + NPTS], fz = flow1[base + 2 * NPTS];
  float sx = x1 + fx, sy = y1 + fy, sz = z1 + fz;
  A[t]  = make_float4(sx, sy, sz, 0.f);
  Bq[t] = make_float4(x1, y1, z1, 0.f);
  float x2 = xyz2[base], y2 = xyz2[base + NPTS], z2 = xyz2[base + 2 * NPTS];
  Qx[t] = make_float4(x2, y2, z2, 0.f);
}

// ---------------- feat2 [B,D,N] -> F [B,N,D]
__global__ void k_feat_T(const float* __restrict__ feat2, float* __restrict__ F) {
  __shared__ float t[64][65];
  int b = blockIdx.y;
  int n0 = blockIdx.x * 64;
  int l = threadIdx.x & 63, w = threadIdx.x >> 6;
#pragma unroll
  for (int it = 0; it < 16; ++it) {
    int dd = w + it * 4;
    t[dd][l] = feat2[((size_t)b * DF + dd) * NPTS + n0 + l];
  }
  __syncthreads();
#pragma unroll
  for (int it = 0; it < 16; ++it) {
    int nn = w + it * 4;
    F[((size_t)b * NPTS + n0 + nn) * DF + l] = t[l][nn];
  }
}

// ---------------- W1 [128][67] -> W1T [67][128]
__global__ void k_w1t(const float* __restrict__ W1, float* __restrict__ W1T) {
  int t = blockIdx.x * 256 + threadIdx.x;
  if (t >= 67 * 128) return;
  int c = t >> 7, h = t & 127;
  W1T[t] = W1[h * 67 + c];
}

// ---------------- W2 [64][128] -> bf16 fragment order: frag=(step*4+ot), lane, j
__global__ void k_w2frag(const float* __restrict__ W2, unsigned short* __restrict__ W2f) {
  int t = blockIdx.x * 256 + threadIdx.x;   // 0..1023
  if (t >= 1024) return;
  int frag = t >> 6, lane = t & 63;
  int step = frag >> 2, ot = frag & 3;
  int col = ot * 16 + (lane & 15);
  int k0 = step * 32 + (lane >> 4) * 8;
#pragma unroll
  for (int j = 0; j < 8; ++j)
    W2f[t * 8 + j] = f2bf(W2[col * HID + k0 + j]);
}

// ---------------- Hfeat[pt][h] = b1[h] + sum_c F[pt][c] * W1T[3+c][h]
__global__ void k_hfeat(const float* __restrict__ F, const float* __restrict__ W1T,
                        const float* __restrict__ b1, float* __restrict__ Hfeat) {
  int tid = threadIdx.x;
  int pt = blockIdx.x * 2 + (tid >> 7);     // 2 points per 256-thread block
  int h = tid & 127;
  const float* fr = F + (size_t)pt * DF;
  float a = b1[h];
#pragma unroll
  for (int c = 0; c < DF; ++c) a = fmaf(fr[c], W1T[(3 + c) * HID + h], a);
  Hfeat[(size_t)pt * HID + h] = a;          // NO leaky (xyz part added later)
}

// ---------------- bitonic full-sort of 64 (d,idx) pairs across lanes, lex ascending
__device__ __forceinline__ void bitonic64(float& d, int& i, int lane) {
#pragma unroll
  for (int k2 = 2; k2 <= 64; k2 <<= 1) {
#pragma unroll
    for (int j2 = k2 >> 1; j2 > 0; j2 >>= 1) {
      float pd = __shfl_xor(d, j2);
      int   pi = __shfl_xor(i, j2);
      bool swp = (pd < d) || (pd == d && pi < i);           // partner strictly smaller
      bool take = (((lane & k2) == 0) == ((lane & j2) == 0)) ? swp : !swp;
      d = take ? pd : d;
      i = take ? pi : i;
    }
  }
}

// ---------------- wave-wide sorted-list insert of ballot'd candidates
template<int K>
__device__ __forceinline__ void wave_insert(unsigned long long m, float d, int pid,
                                            int lane, float& ld, int& li, float& cap, int& ci) {
  do {
    int c = __ffsll(m) - 1; m &= m - 1;
    float bd = readlane_f(d, c); int bi = readlane_i(pid, c);
    bool pred = (ld > bd) || (ld == bd && li > bi);
    unsigned long long pm = __ballot(pred);
    float sld = __shfl_up(ld, 1);
    int   sli = __shfl_up(li, 1);
    bool pp = lane ? ((pm >> (lane - 1)) & 1ull) : false;
    ld = pred ? (pp ? sld : bd) : ld;
    li = pred ? (pp ? sli : bi) : li;
    cap = readlane_f(ld, K - 1); ci = readlane_i(li, K - 1);
    if (m) m &= __ballot((d < cap) || (d == cap && pid < ci));
  } while (m);
}

// ================ LDS-staged brute-force exact KNN ================
// Block = 4 waves = 8 queries (same batch); 2048 blocks -> 8 blocks/CU = 32
// waves/CU (insert-chain latency hidden by TLP). DB staged chunk-by-chunk in
// LDS, shared by the 8 queries. Wave handles 2 queries: lane-distributed
// sorted top-K per query, bitonic bootstrap on first 64 pts.
template<int K>
__global__ void __launch_bounds__(256) k_knn_lds(const float4* __restrict__ db,
                                                 const float4* __restrict__ qry,
                                                 int* __restrict__ outIdx) {
  __shared__ float4 tile[1024];
  int bk = blockIdx.x;                       // 0..2047
  int b = bk >> 10;                          // batch (1024 blocks each)
  int wave = threadIdx.x >> 6, lane = threadIdx.x & 63;
  int qb = bk * 8 + wave * 2;
  float4 Q0 = qry[qb], Q1 = qry[qb + 1];
  const float4* dbase = db + (size_t)b * NPTS;

#pragma unroll
  for (int i = 0; i < 4; ++i) tile[threadIdx.x + i * 256] = dbase[threadIdx.x + i * 256];
  __syncthreads();

  // bootstrap: bitonic-sort distances to points 0..63 for each query
  float ld0, ld1; int li0 = lane, li1 = lane;
  {
    float4 p = tile[lane];
    float dx = Q0.x - p.x, dy = Q0.y - p.y, dz = Q0.z - p.z;
    ld0 = fmaf(dx, dx, fmaf(dy, dy, dz * dz));
    dx = Q1.x - p.x; dy = Q1.y - p.y; dz = Q1.z - p.z;
    ld1 = fmaf(dx, dx, fmaf(dy, dy, dz * dz));
  }
  bitonic64(ld0, li0, lane);
  bitonic64(ld1, li1, lane);
  float cap0 = readlane_f(ld0, K - 1), cap1 = readlane_f(ld1, K - 1);
  int ci0 = readlane_i(li0, K - 1), ci1 = readlane_i(li1, K - 1);

  for (int chunk = 0; chunk < 8; ++chunk) {
    if (chunk) {
      __syncthreads();
#pragma unroll
      for (int i = 0; i < 4; ++i)
        tile[threadIdx.x + i * 256] = dbase[chunk * 1024 + threadIdx.x + i * 256];
      __syncthreads();
    }
    for (int it = (chunk == 0) ? 1 : 0; it < 16; ++it) {
      int j = chunk * 1024 + it * 64 + lane;
      float4 p = tile[it * 64 + lane];
      float ax = Q0.x - p.x, ay = Q0.y - p.y, az = Q0.z - p.z;
      float d0 = fmaf(ax, ax, fmaf(ay, ay, az * az));
      float bx = Q1.x - p.x, by = Q1.y - p.y, bz = Q1.z - p.z;
      float d1 = fmaf(bx, bx, fmaf(by, by, bz * bz));

      unsigned long long m0 = __ballot((d0 < cap0) || (d0 == cap0 && j < ci0));
      if (m0) wave_insert<K>(m0, d0, j, lane, ld0, li0, cap0, ci0);
      unsigned long long m1 = __ballot((d1 < cap1) || (d1 == cap1 && j < ci1));
      if (m1) wave_insert<K>(m1, d1, j, lane, ld1, li1, cap1, ci1);
    }
  }
  if (lane < K) {
    outIdx[(qb + 0) * K + lane] = li0;
    outIdx[(qb + 1) * K + lane] = li1;
  }
}

// ---------------- 3-NN inverse-distance warp interpolation
__global__ void k_warp_finish(const int* __restrict__ idx3,
                              const float4* __restrict__ A, const float4* __restrict__ Qx,
                              const float* __restrict__ flow1, float* __restrict__ out1,
                              float4* __restrict__ C) {
  int qg = blockIdx.x * 256 + threadIdx.x;
  int b = qg >> 13, n = qg & (NPTS - 1);
  int idx[3];
#pragma unroll
  for (int r = 0; r < 3; ++r) idx[r] = idx3[qg * 3 + r];
  float4 q = Qx[qg];
  float ivd[3];
  float s = 0.f;
#pragma unroll
  for (int r = 0; r < 3; ++r) {
    float4 p = A[b * NPTS + idx[r]];
    float gx = p.x - q.x, gy = p.y - q.y, gz = p.z - q.z;
    float dist = sqrtf(gx * gx + gy * gy + gz * gz);
    dist = fmaxf(dist, 1e-10f);
    ivd[r] = 1.0f / dist;
    s += ivd[r];
  }
  float w0 = ivd[0] / s, w1 = ivd[1] / s, w2 = ivd[2] / s;
  size_t fb = (size_t)b * 3 * NPTS;
  float f2x = w0 * flow1[fb + idx[0]]            + w1 * flow1[fb + idx[1]]            + w2 * flow1[fb + idx[2]];
  float f2y = w0 * flow1[fb + NPTS + idx[0]]     + w1 * flow1[fb + NPTS + idx[1]]     + w2 * flow1[fb + NPTS + idx[2]];
  float f2z = w0 * flow1[fb + 2 * NPTS + idx[0]] + w1 * flow1[fb + 2 * NPTS + idx[1]] + w2 * flow1[fb + 2 * NPTS + idx[2]];
  float wx = q.x - f2x, wy = q.y - f2y, wz = q.z - f2z;
  out1[fb + n] = wx;
  out1[fb + NPTS + n] = wy;
  out1[fb + 2 * NPTS + n] = wz;
  C[qg] = make_float4(wx, wy, wz, 0.f);
}

// ---------------- MFMA MLP (unchanged)
__global__ void __launch_bounds__(256) k_mlp3(const int* __restrict__ Didx, const float4* __restrict__ C,
                                              const float4* __restrict__ Bq, const float* __restrict__ Hfeat,
                                              const float* __restrict__ W1T, const unsigned short* __restrict__ W2f,
                                              const float* __restrict__ b2, float* __restrict__ out0) {
  int lane = threadIdx.x & 63;
  int wg = blockIdx.x * 4 + (threadIdx.x >> 6);    // 0..4095, 4 q per wave
  int fr = lane & 15, fq = lane >> 4;

  short8v Bfr[16];
  const short8v* wf = (const short8v*)W2f;
#pragma unroll
  for (int i = 0; i < 16; ++i) Bfr[i] = wf[i * 64 + lane];
  float b2v0 = b2[fr], b2v1 = b2[16 + fr], b2v2 = b2[32 + fr], b2v3 = b2[48 + fr];

  for (int iq = 0; iq < 4; ++iq) {
    int q = wg * 4 + iq;
    int b = q >> 13, n = q & (NPTS - 1);
    int idx = Didx[q * KNN + fr];
    float4 wp = C[b * NPTS + idx];
    float4 qp = Bq[q];
    float dx = wp.x - qp.x, dy = wp.y - qp.y, dz = wp.z - qp.z;
    const float* hf = Hfeat + ((size_t)(b * NPTS + idx)) * HID;

    f32x4 acc0 = {b2v0, b2v0, b2v0, b2v0};
    f32x4 acc1 = {b2v1, b2v1, b2v1, b2v1};
    f32x4 acc2 = {b2v2, b2v2, b2v2, b2v2};
    f32x4 acc3 = {b2v3, b2v3, b2v3, b2v3};

#pragma unroll
    for (int step = 0; step < 4; ++step) {
      int k0 = step * 32 + fq * 8;
      float4 ha = *(const float4*)(hf + k0);
      float4 hb = *(const float4*)(hf + k0 + 4);
      float4 wx0 = *(const float4*)(W1T + k0);
      float4 wx1 = *(const float4*)(W1T + k0 + 4);
      float4 wy0 = *(const float4*)(W1T + HID + k0);
      float4 wy1 = *(const float4*)(W1T + HID + k0 + 4);
      float4 wz0 = *(const float4*)(W1T + 2 * HID + k0);
      float4 wz1 = *(const float4*)(W1T + 2 * HID + k0 + 4);
      float h[8];
      h[0] = fmaf(dx, wx0.x, fmaf(dy, wy0.x, fmaf(dz, wz0.x, ha.x)));
      h[1] = fmaf(dx, wx0.y, fmaf(dy, wy0.y, fmaf(dz, wz0.y, ha.y)));
      h[2] = fmaf(dx, wx0.z, fmaf(dy, wy0.z, fmaf(dz, wz0.z, ha.z)));
      h[3] = fmaf(dx, wx0.w, fmaf(dy, wy0.w, fmaf(dz, wz0.w, ha.w)));
      h[4] = fmaf(dx, wx1.x, fmaf(dy, wy1.x, fmaf(dz, wz1.x, hb.x)));
      h[5] = fmaf(dx, wx1.y, fmaf(dy, wy1.y, fmaf(dz, wz1.y, hb.y)));
      h[6] = fmaf(dx, wx1.z, fmaf(dy, wy1.z, fmaf(dz, wz1.z, hb.z)));
      h[7] = fmaf(dx, wx1.w, fmaf(dy, wy1.w, fmaf(dz, wz1.w, hb.w)));
      short8v a;
#pragma unroll
      for (int j = 0; j < 8; ++j) {
        float v = h[j];
        v = v >= 0.f ? v : 0.1f * v;
        a[j] = (short)f2bf(v);
      }
      acc0 = __builtin_amdgcn_mfma_f32_16x16x32_bf16(a, Bfr[step * 4 + 0], acc0, 0, 0, 0);
      acc1 = __builtin_amdgcn_mfma_f32_16x16x32_bf16(a, Bfr[step * 4 + 1], acc1, 0, 0, 0);
      acc2 = __builtin_amdgcn_mfma_f32_16x16x32_bf16(a, Bfr[step * 4 + 2], acc2, 0, 0, 0);
      acc3 = __builtin_amdgcn_mfma_f32_16x16x32_bf16(a, Bfr[step * 4 + 3], acc3, 0, 0, 0);
    }

    int ob = (b * OUTC) * NPTS + n;
#pragma unroll
    for (int ot = 0; ot < 4; ++ot) {
      f32x4 ac = ot == 0 ? acc0 : (ot == 1 ? acc1 : (ot == 2 ? acc2 : acc3));
      float m = fmaxf(fmaxf(ac[0], ac[1]), fmaxf(ac[2], ac[3]));
      m = fmaxf(m, __shfl_xor(m, 16));
      m = fmaxf(m, __shfl_xor(m, 32));
      m = m >= 0.f ? m : 0.1f * m;
      if (lane < 16) out0[ob + (ot * 16 + lane) * NPTS] = m;
    }
  }
}

extern "C" void kernel_launch(void* const* d_in, const int* in_sizes, int n_in,
                              void* d_out, int out_size, void* d_ws, size_t ws_size,
                              hipStream_t stream) {
  const float* xyz1  = (const float*)d_in[0];
  const float* xyz2  = (const float*)d_in[1];
  const float* flow1 = (const float*)d_in[2];
  const float* feat2 = (const float*)d_in[3];
  const float* W1    = (const float*)d_in[4];
  const float* b1    = (const float*)d_in[5];
  const float* W2    = (const float*)d_in[6];
  const float* b2    = (const float*)d_in[7];
  float* out0 = (float*)d_out;
  float* out1 = out0 + (size_t)NB * OUTC * NPTS;

  float* w = (float*)d_ws;
  float4* A     = (float4*)(w);             // 65536 floats
  float4* Bq    = (float4*)(w + 65536);
  float4* Qx    = (float4*)(w + 131072);
  float4* Cw    = (float4*)(w + 196608);
  float*  F     = w + 262144;               // 1048576
  float*  Hfeat = w + 1310720;              // 2097152
  float*  W1T   = w + 3407872;              // 16384 (8576 used)
  int*    idx3  = (int*)(w + 3424256);      // 49152
  int*    Didx  = (int*)(w + 3473408);      // 262144
  unsigned short* W2f = (unsigned short*)(w + 3735552);  // 8192 bf16

  k_prep<<<64, 256, 0, stream>>>(xyz1, xyz2, flow1, A, Bq, Qx);
  k_feat_T<<<dim3(128, 2), 256, 0, stream>>>(feat2, F);
  k_w1t<<<34, 256, 0, stream>>>(W1, W1T);
  k_w2frag<<<4, 256, 0, stream>>>(W2, W2f);
  k_hfeat<<<NB * NPTS / 2, 256, 0, stream>>>(F, W1T, b1, Hfeat);

  k_knn_lds<3><<<2048, 256, 0, stream>>>(A, Qx, idx3);
  k_warp_finish<<<64, 256, 0, stream>>>(idx3, A, Qx, flow1, out1, Cw);
  k_knn_lds<16><<<2048, 256, 0, stream>>>(Cw, Bq, Didx);
  k_mlp3<<<1024, 256, 0, stream>>>(Didx, Cw, Bq, Hfeat, W1T, W2f, b2, out0);
}

// Round 24
// 238.656 us; speedup vs baseline: 1.3258x; 1.0962x over previous
//
#include <hip/hip_runtime.h>
#include <math.h>

#define NPTS 8192
#define NB 2
#define DF 64
#define HID 128
#define OUTC 64
#define KNN 16

typedef __attribute__((ext_vector_type(8))) short short8v;   // 8 bf16 (4 VGPRs)
typedef __attribute__((ext_vector_type(4))) float f32x4;

__device__ __forceinline__ unsigned short f2bf(float f) {    // f32 -> bf16 RNE
  unsigned int u = __float_as_uint(f);
  u += 0x7fffu + ((u >> 16) & 1u);
  return (unsigned short)(u >> 16);
}

__device__ __forceinline__ float readlane_f(float v, int l) {
  return __uint_as_float(__builtin_amdgcn_readlane(__float_as_uint(v), l));
}
__device__ __forceinline__ int readlane_i(int v, int l) {
  return (int)__builtin_amdgcn_readlane((unsigned)v, l);
}

// ---------------- prep: pack points as float4(x,y,z,0)
__global__ void k_prep(const float* __restrict__ xyz1, const float* __restrict__ xyz2,
                       const float* __restrict__ flow1,
                       float4* __restrict__ A, float4* __restrict__ Bq, float4* __restrict__ Qx) {
  int t = blockIdx.x * 256 + threadIdx.x;      // 0..16383
  int b = t >> 13, n = t & (NPTS - 1);
  size_t base = (size_t)b * 3 * NPTS + n;
  float x1 = xyz1[base], y1 = xyz1[base + NPTS], z1 = xyz1[base + 2 * NPTS];
  float fx = flow1[base], fy = flow1[base + NPTS], fz = flow1[base + 2 * NPTS];
  float sx = x1 + fx, sy = y1 + fy, sz = z1 + fz;
  A[t]  = make_float4(sx, sy, sz, 0.f);
  Bq[t] = make_float4(x1, y1, z1, 0.f);
  float x2 = xyz2[base], y2 = xyz2[base + NPTS], z2 = xyz2[base + 2 * NPTS];
  Qx[t] = make_float4(x2, y2, z2, 0.f);
}

// ---------------- feat2 [B,D,N] -> F [B,N,D]
__global__ void k_feat_T(const float* __restrict__ feat2, float* __restrict__ F) {
  __shared__ float t[64][65];
  int b = blockIdx.y;
  int n0 = blockIdx.x * 64;
  int l = threadIdx.x & 63, w = threadIdx.x >> 6;
#pragma unroll
  for (int it = 0; it < 16; ++it) {
    int dd = w + it * 4;
    t[dd][l] = feat2[((size_t)b * DF + dd) * NPTS + n0 + l];
  }
  __syncthreads();
#pragma unroll
  for (int it = 0; it < 16; ++it) {
    int nn = w + it * 4;
    F[((size_t)b * NPTS + n0 + nn) * DF + l] = t[l][nn];
  }
}

// ---------------- W1 [128][67] -> W1T [67][128]
__global__ void k_w1t(const float* __restrict__ W1, float* __restrict__ W1T) {
  int t = blockIdx.x * 256 + threadIdx.x;
  if (t >= 67 * 128) return;
  int c = t >> 7, h = t & 127;
  W1T[t] = W1[h * 67 + c];
}

// ---------------- W2 [64][128] -> bf16 fragment order: frag=(step*4+ot), lane, j
__global__ void k_w2frag(const float* __restrict__ W2, unsigned short* __restrict__ W2f) {
  int t = blockIdx.x * 256 + threadIdx.x;   // 0..1023
  if (t >= 1024) return;
  int frag = t >> 6, lane = t & 63;
  int step = frag >> 2, ot = frag & 3;
  int col = ot * 16 + (lane & 15);
  int k0 = step * 32 + (lane >> 4) * 8;
#pragma unroll
  for (int j = 0; j < 8; ++j)
    W2f[t * 8 + j] = f2bf(W2[col * HID + k0 + j]);
}

// ---------------- Hfeat[pt][h] = b1[h] + sum_c F[pt][c] * W1T[3+c][h]
__global__ void k_hfeat(const float* __restrict__ F, const float* __restrict__ W1T,
                        const float* __restrict__ b1, float* __restrict__ Hfeat) {
  int tid = threadIdx.x;
  int pt = blockIdx.x * 2 + (tid >> 7);     // 2 points per 256-thread block
  int h = tid & 127;
  const float* fr = F + (size_t)pt * DF;
  float a = b1[h];
#pragma unroll
  for (int c = 0; c < DF; ++c) a = fmaf(fr[c], W1T[(3 + c) * HID + h], a);
  Hfeat[(size_t)pt * HID + h] = a;          // NO leaky (xyz part added later)
}

// ---------------- bitonic full-sort of 64 (d,idx) pairs across lanes, lex ascending
__device__ __forceinline__ void bitonic64(float& d, int& i, int lane) {
#pragma unroll
  for (int k2 = 2; k2 <= 64; k2 <<= 1) {
#pragma unroll
    for (int j2 = k2 >> 1; j2 > 0; j2 >>= 1) {
      float pd = __shfl_xor(d, j2);
      int   pi = __shfl_xor(i, j2);
      bool swp = (pd < d) || (pd == d && pi < i);           // partner strictly smaller
      bool take = (((lane & k2) == 0) == ((lane & j2) == 0)) ? swp : !swp;
      d = take ? pd : d;
      i = take ? pi : i;
    }
  }
}

// ---------------- wave-wide sorted-list insert of ballot'd candidates
// Exact lex-ordered insertion; superset admissions (ties with larger index)
// insert below position K-1 and cannot perturb the top-K prefix.
template<int K>
__device__ __forceinline__ void wave_insert(unsigned long long m, float d, int pid,
                                            int lane, float& ld, int& li, float& cap, int& ci) {
  do {
    int c = __ffsll(m) - 1; m &= m - 1;
    float bd = readlane_f(d, c); int bi = readlane_i(pid, c);
    bool pred = (ld > bd) || (ld == bd && li > bi);
    unsigned long long pm = __ballot(pred);
    float sld = __shfl_up(ld, 1);
    int   sli = __shfl_up(li, 1);
    bool pp = lane ? ((pm >> (lane - 1)) & 1ull) : false;
    ld = pred ? (pp ? sld : bd) : ld;
    li = pred ? (pp ? sli : bi) : li;
    cap = readlane_f(ld, K - 1); ci = readlane_i(li, K - 1);
    if (m) m &= __ballot((d < cap) || (d == cap && pid < ci));
  } while (m);
}

// ================ LDS-staged brute-force exact KNN ================
// Block = 4 waves = 8 queries (same batch); 2048 blocks -> 8 blocks/CU = 32
// waves/CU. Scan admission is a single v_cmp (d <= cap): superset of the exact
// predicate; wave_insert's lex insertion keeps top-K exact (ties -> lowest
// index, jax semantics). Saves ~8 VALU/iter in the issue-bound scan.
template<int K>
__global__ void __launch_bounds__(256) k_knn_lds(const float4* __restrict__ db,
                                                 const float4* __restrict__ qry,
                                                 int* __restrict__ outIdx) {
  __shared__ float4 tile[1024];
  int bk = blockIdx.x;                       // 0..2047
  int b = bk >> 10;                          // batch (1024 blocks each)
  int wave = threadIdx.x >> 6, lane = threadIdx.x & 63;
  int qb = bk * 8 + wave * 2;
  float4 Q0 = qry[qb], Q1 = qry[qb + 1];
  const float4* dbase = db + (size_t)b * NPTS;

#pragma unroll
  for (int i = 0; i < 4; ++i) tile[threadIdx.x + i * 256] = dbase[threadIdx.x + i * 256];
  __syncthreads();

  // bootstrap: bitonic-sort distances to points 0..63 for each query
  float ld0, ld1; int li0 = lane, li1 = lane;
  {
    float4 p = tile[lane];
    float dx = Q0.x - p.x, dy = Q0.y - p.y, dz = Q0.z - p.z;
    ld0 = fmaf(dx, dx, fmaf(dy, dy, dz * dz));
    dx = Q1.x - p.x; dy = Q1.y - p.y; dz = Q1.z - p.z;
    ld1 = fmaf(dx, dx, fmaf(dy, dy, dz * dz));
  }
  bitonic64(ld0, li0, lane);
  bitonic64(ld1, li1, lane);
  float cap0 = readlane_f(ld0, K - 1), cap1 = readlane_f(ld1, K - 1);
  int ci0 = readlane_i(li0, K - 1), ci1 = readlane_i(li1, K - 1);

  for (int chunk = 0; chunk < 8; ++chunk) {
    if (chunk) {
      __syncthreads();
#pragma unroll
      for (int i = 0; i < 4; ++i)
        tile[threadIdx.x + i * 256] = dbase[chunk * 1024 + threadIdx.x + i * 256];
      __syncthreads();
    }
    for (int it = (chunk == 0) ? 1 : 0; it < 16; ++it) {
      int j = chunk * 1024 + it * 64 + lane;
      float4 p = tile[it * 64 + lane];
      float ax = Q0.x - p.x, ay = Q0.y - p.y, az = Q0.z - p.z;
      float d0 = fmaf(ax, ax, fmaf(ay, ay, az * az));
      float bx = Q1.x - p.x, by = Q1.y - p.y, bz = Q1.z - p.z;
      float d1 = fmaf(bx, bx, fmaf(by, by, bz * bz));

      unsigned long long m0 = __ballot(d0 <= cap0);   // superset admission, 1 v_cmp
      if (m0) wave_insert<K>(m0, d0, j, lane, ld0, li0, cap0, ci0);
      unsigned long long m1 = __ballot(d1 <= cap1);
      if (m1) wave_insert<K>(m1, d1, j, lane, ld1, li1, cap1, ci1);
    }
  }
  if (lane < K) {
    outIdx[(qb + 0) * K + lane] = li0;
    outIdx[(qb + 1) * K + lane] = li1;
  }
}

// ---------------- 3-NN inverse-distance warp interpolation
__global__ void k_warp_finish(const int* __restrict__ idx3,
                              const float4* __restrict__ A, const float4* __restrict__ Qx,
                              const float* __restrict__ flow1, float* __restrict__ out1,
                              float4* __restrict__ C) {
  int qg = blockIdx.x * 256 + threadIdx.x;
  int b = qg >> 13, n = qg & (NPTS - 1);
  int idx[3];
#pragma unroll
  for (int r = 0; r < 3; ++r) idx[r] = idx3[qg * 3 + r];
  float4 q = Qx[qg];
  float ivd[3];
  float s = 0.f;
#pragma unroll
  for (int r = 0; r < 3; ++r) {
    float4 p = A[b * NPTS + idx[r]];
    float gx = p.x - q.x, gy = p.y - q.y, gz = p.z - q.z;
    float dist = sqrtf(gx * gx + gy * gy + gz * gz);
    dist = fmaxf(dist, 1e-10f);
    ivd[r] = 1.0f / dist;
    s += ivd[r];
  }
  float w0 = ivd[0] / s, w1 = ivd[1] / s, w2 = ivd[2] / s;
  size_t fb = (size_t)b * 3 * NPTS;
  float f2x = w0 * flow1[fb + idx[0]]            + w1 * flow1[fb + idx[1]]            + w2 * flow1[fb + idx[2]];
  float f2y = w0 * flow1[fb + NPTS + idx[0]]     + w1 * flow1[fb + NPTS + idx[1]]     + w2 * flow1[fb + NPTS + idx[2]];
  float f2z = w0 * flow1[fb + 2 * NPTS + idx[0]] + w1 * flow1[fb + 2 * NPTS + idx[1]] + w2 * flow1[fb + 2 * NPTS + idx[2]];
  float wx = q.x - f2x, wy = q.y - f2y, wz = q.z - f2z;
  out1[fb + n] = wx;
  out1[fb + NPTS + n] = wy;
  out1[fb + 2 * NPTS + n] = wz;
  C[qg] = make_float4(wx, wy, wz, 0.f);
}

// ---------------- MFMA MLP (unchanged)
__global__ void __launch_bounds__(256) k_mlp3(const int* __restrict__ Didx, const float4* __restrict__ C,
                                              const float4* __restrict__ Bq, const float* __restrict__ Hfeat,
                                              const float* __restrict__ W1T, const unsigned short* __restrict__ W2f,
                                              const float* __restrict__ b2, float* __restrict__ out0) {
  int lane = threadIdx.x & 63;
  int wg = blockIdx.x * 4 + (threadIdx.x >> 6);    // 0..4095, 4 q per wave
  int fr = lane & 15, fq = lane >> 4;

  short8v Bfr[16];
  const short8v* wf = (const short8v*)W2f;
#pragma unroll
  for (int i = 0; i < 16; ++i) Bfr[i] = wf[i * 64 + lane];
  float b2v0 = b2[fr], b2v1 = b2[16 + fr], b2v2 = b2[32 + fr], b2v3 = b2[48 + fr];

  for (int iq = 0; iq < 4; ++iq) {
    int q = wg * 4 + iq;
    int b = q >> 13, n = q & (NPTS - 1);
    int idx = Didx[q * KNN + fr];
    float4 wp = C[b * NPTS + idx];
    float4 qp = Bq[q];
    float dx = wp.x - qp.x, dy = wp.y - qp.y, dz = wp.z - qp.z;
    const float* hf = Hfeat + ((size_t)(b * NPTS + idx)) * HID;

    f32x4 acc0 = {b2v0, b2v0, b2v0, b2v0};
    f32x4 acc1 = {b2v1, b2v1, b2v1, b2v1};
    f32x4 acc2 = {b2v2, b2v2, b2v2, b2v2};
    f32x4 acc3 = {b2v3, b2v3, b2v3, b2v3};

#pragma unroll
    for (int step = 0; step < 4; ++step) {
      int k0 = step * 32 + fq * 8;
      float4 ha = *(const float4*)(hf + k0);
      float4 hb = *(const float4*)(hf + k0 + 4);
      float4 wx0 = *(const float4*)(W1T + k0);
      float4 wx1 = *(const float4*)(W1T + k0 + 4);
      float4 wy0 = *(const float4*)(W1T + HID + k0);
      float4 wy1 = *(const float4*)(W1T + HID + k0 + 4);
      float4 wz0 = *(const float4*)(W1T + 2 * HID + k0);
      float4 wz1 = *(const float4*)(W1T + 2 * HID + k0 + 4);
      float h[8];
      h[0] = fmaf(dx, wx0.x, fmaf(dy, wy0.x, fmaf(dz, wz0.x, ha.x)));
      h[1] = fmaf(dx, wx0.y, fmaf(dy, wy0.y, fmaf(dz, wz0.y, ha.y)));
      h[2] = fmaf(dx, wx0.z, fmaf(dy, wy0.z, fmaf(dz, wz0.z, ha.z)));
      h[3] = fmaf(dx, wx0.w, fmaf(dy, wy0.w, fmaf(dz, wz0.w, ha.w)));
      h[4] = fmaf(dx, wx1.x, fmaf(dy, wy1.x, fmaf(dz, wz1.x, hb.x)));
      h[5] = fmaf(dx, wx1.y, fmaf(dy, wy1.y, fmaf(dz, wz1.y, hb.y)));
      h[6] = fmaf(dx, wx1.z, fmaf(dy, wy1.z, fmaf(dz, wz1.z, hb.z)));
      h[7] = fmaf(dx, wx1.w, fmaf(dy, wy1.w, fmaf(dz, wz1.w, hb.w)));
      short8v a;
#pragma unroll
      for (int j = 0; j < 8; ++j) {
        float v = h[j];
        v = v >= 0.f ? v : 0.1f * v;
        a[j] = (short)f2bf(v);
      }
      acc0 = __builtin_amdgcn_mfma_f32_16x16x32_bf16(a, Bfr[step * 4 + 0], acc0, 0, 0, 0);
      acc1 = __builtin_amdgcn_mfma_f32_16x16x32_bf16(a, Bfr[step * 4 + 1], acc1, 0, 0, 0);
      acc2 = __builtin_amdgcn_mfma_f32_16x16x32_bf16(a, Bfr[step * 4 + 2], acc2, 0, 0, 0);
      acc3 = __builtin_amdgcn_mfma_f32_16x16x32_bf16(a, Bfr[step * 4 + 3], acc3, 0, 0, 0);
    }

    int ob = (b * OUTC) * NPTS + n;
#pragma unroll
    for (int ot = 0; ot < 4; ++ot) {
      f32x4 ac = ot == 0 ? acc0 : (ot == 1 ? acc1 : (ot == 2 ? acc2 : acc3));
      float m = fmaxf(fmaxf(ac[0], ac[1]), fmaxf(ac[2], ac[3]));
      m = fmaxf(m, __shfl_xor(m, 16));
      m = fmaxf(m, __shfl_xor(m, 32));
      m = m >= 0.f ? m : 0.1f * m;
      if (lane < 16) out0[ob + (ot * 16 + lane) * NPTS] = m;
    }
  }
}

extern "C" void kernel_launch(void* const* d_in, const int* in_sizes, int n_in,
                              void* d_out, int out_size, void* d_ws, size_t ws_size,
                              hipStream_t stream) {
  const float* xyz1  = (const float*)d_in[0];
  const float* xyz2  = (const float*)d_in[1];
  const float* flow1 = (const float*)d_in[2];
  const float* feat2 = (const float*)d_in[3];
  const float* W1    = (const float*)d_in[4];
  const float* b1    = (const float*)d_in[5];
  const float* W2    = (const float*)d_in[6];
  const float* b2    = (const float*)d_in[7];
  float* out0 = (float*)d_out;
  float* out1 = out0 + (size_t)NB * OUTC * NPTS;

  float* w = (float*)d_ws;
  float4* A     = (float4*)(w);             // 65536 floats
  float4* Bq    = (float4*)(w + 65536);
  float4* Qx    = (float4*)(w + 131072);
  float4* Cw    = (float4*)(w + 196608);
  float*  F     = w + 262144;               // 1048576
  float*  Hfeat = w + 1310720;              // 2097152
  float*  W1T   = w + 3407872;              // 16384 (8576 used)
  int*    idx3  = (int*)(w + 3424256);      // 49152
  int*    Didx  = (int*)(w + 3473408);      // 262144
  unsigned short* W2f = (unsigned short*)(w + 3735552);  // 8192 bf16

  k_prep<<<64, 256, 0, stream>>>(xyz1, xyz2, flow1, A, Bq, Qx);
  k_feat_T<<<dim3(128, 2), 256, 0, stream>>>(feat2, F);
  k_w1t<<<34, 256, 0, stream>>>(W1, W1T);
  k_w2frag<<<4, 256, 0, stream>>>(W2, W2f);
  k_hfeat<<<NB * NPTS / 2, 256, 0, stream>>>(F, W1T, b1, Hfeat);

  k_knn_lds<3><<<2048, 256, 0, stream>>>(A, Qx, idx3);
  k_warp_finish<<<64, 256, 0, stream>>>(idx3, A, Qx, flow1, out1, Cw);
  k_knn_lds<16><<<2048, 256, 0, stream>>>(Cw, Bq, Didx);
  k_mlp3<<<1024, 256, 0, stream>>>(Didx, Cw, Bq, Hfeat, W1T, W2f, b2, out0);
}